// Round 3
// baseline (363.614 us; speedup 1.0000x reference)
//
#include <hip/hip_runtime.h>

// x        [64, 524288] f32 | idx_feat [4096,256] f32 | weight [64,256] f32
// bias     [64] f32         | pred_cate [4096] i32    | pred_score [4096] f32
// out (f32 concat): seg_pred [53*524288], unique_cate [53], fused_score [53]

#define KK   4096
#define CIN  256
#define CC   64
#define HW   524288   // 512*1024
#define HW4  (HW / 4)
#define UU   53

// ws layout (floats): gsum [53*256], gsc [64], gcnt [64], fw [53*64]
#define WS_GSUM  0
#define WS_GSC   (UU * CIN)          // 13568
#define WS_GCNT  (WS_GSC + 64)       // 13632
#define WS_FW    (WS_GCNT + 64)      // 13696
#define WS_ZERO_FLOATS WS_FW         // zero gsum+gsc+gcnt

// ---------------------------------------------------------------------------
// Stage 1: fully-parallel segment accumulation via device-scope atomics.
// 4096 blocks (one row of idx_feat each). Per-address contention ~77 adds;
// float-order nondeterminism is ~1e-7 relative — far under the 2% threshold.
// ---------------------------------------------------------------------------
__global__ __launch_bounds__(256)
void accum_kernel(const float* __restrict__ idx_feat,
                  const int*   __restrict__ pred_cate,
                  const float* __restrict__ pred_score,
                  float* __restrict__ ws)
{
    const int k   = blockIdx.x;
    const int tid = threadIdx.x;
    const int cls = pred_cate[k];                       // wave-uniform
    atomicAdd(&ws[WS_GSUM + cls * CIN + tid], idx_feat[(size_t)k * CIN + tid]);
    if (tid == 0) {
        atomicAdd(&ws[WS_GSC  + cls], pred_score[k]);
        atomicAdd(&ws[WS_GCNT + cls], 1.0f);
    }
}

// ---------------------------------------------------------------------------
// Stage 2: project class-mean features through weight/bias -> fw [53][64].
// One block per class, 64 threads (one per output channel). gsum row is
// wave-uniform -> scalar loads; weight rows stream through L1/L2 (64 KB).
// Also writes unique_cate and fused_score.
// ---------------------------------------------------------------------------
__global__ __launch_bounds__(64)
void project_kernel(const float* __restrict__ ws_ro,
                    const float* __restrict__ weight,
                    const float* __restrict__ bias,
                    float* __restrict__ ws,
                    float* __restrict__ out)
{
    const int u = blockIdx.x;
    const int c = threadIdx.x;
    const float inv = 1.0f / ws_ro[WS_GCNT + u];

    float d = 0.0f;
    #pragma unroll 8
    for (int i = 0; i < CIN; ++i)
        d = fmaf(ws_ro[WS_GSUM + u * CIN + i], weight[(size_t)c * CIN + i], d);
    ws[WS_FW + u * CC + c] = d * inv + bias[c];

    if (c == 0) {
        out[(size_t)UU * HW + u]      = (float)u;              // unique_cate
        out[(size_t)UU * HW + UU + u] = ws_ro[WS_GSC + u] * inv; // fused_score
    }
}

// ---------------------------------------------------------------------------
// Stage 3: seg_pred = fw [53,64] @ x [64, HW], float4-vectorized, u-tiled.
// Thread owns 4 columns; u split into tiles {14,14,14,11} so acc fits in
// <=56 VGPRs. Blocks ordered (j_tile major, u_tile minor) so the 4 u-tiles
// sharing a j-tile are dispatch-adjacent -> x fetched from HBM ~once, the
// re-reads hit the die-level L3. fw indexed wave-uniformly -> s_loads.
// ---------------------------------------------------------------------------
template<int NU>
__device__ __forceinline__
void seg_tile(const float4* __restrict__ x4, const float* __restrict__ fw,
              float4* __restrict__ out4, int u0, int jv)
{
    float4 acc[NU];
    #pragma unroll
    for (int i = 0; i < NU; ++i) acc[i] = make_float4(0.f, 0.f, 0.f, 0.f);

    #pragma unroll 4
    for (int c = 0; c < CC; ++c) {
        const float4 xv = x4[(size_t)c * HW4 + jv];
        #pragma unroll
        for (int i = 0; i < NU; ++i) {
            const float w = fw[(u0 + i) * CC + c];   // wave-uniform
            acc[i].x = fmaf(w, xv.x, acc[i].x);
            acc[i].y = fmaf(w, xv.y, acc[i].y);
            acc[i].z = fmaf(w, xv.z, acc[i].z);
            acc[i].w = fmaf(w, xv.w, acc[i].w);
        }
    }
    #pragma unroll
    for (int i = 0; i < NU; ++i)
        out4[(size_t)(u0 + i) * HW4 + jv] = acc[i];
}

__global__ __launch_bounds__(256)
void seg_pred_kernel(const float* __restrict__ x,
                     const float* __restrict__ ws,
                     float* __restrict__ out)
{
    const int ut = blockIdx.x & 3;
    const int jt = blockIdx.x >> 2;
    const int jv = jt * 256 + threadIdx.x;      // float4 column index
    const float4* x4   = (const float4*)x;
    float4*       out4 = (float4*)out;
    const float*  fw   = ws + WS_FW;

    if (ut < 3) seg_tile<14>(x4, fw, out4, ut * 14, jv);
    else        seg_tile<11>(x4, fw, out4, 42,      jv);
}

extern "C" void kernel_launch(void* const* d_in, const int* in_sizes, int n_in,
                              void* d_out, int out_size, void* d_ws, size_t ws_size,
                              hipStream_t stream)
{
    const float* x          = (const float*)d_in[0];
    const float* idx_feat   = (const float*)d_in[1];
    const float* weight     = (const float*)d_in[2];
    const float* bias       = (const float*)d_in[3];
    const int*   pred_cate  = (const int*)d_in[4];
    const float* pred_score = (const float*)d_in[5];

    float* out = (float*)d_out;
    float* ws  = (float*)d_ws;

    // zero the atomic accumulators (ws is re-poisoned 0xAA before each call)
    hipMemsetAsync(ws, 0, (size_t)WS_ZERO_FLOATS * sizeof(float), stream);

    accum_kernel<<<KK, 256, 0, stream>>>(idx_feat, pred_cate, pred_score, ws);
    project_kernel<<<UU, 64, 0, stream>>>(ws, weight, bias, ws, out);
    // 4 u-tiles x (HW/4/256)=512 j-tiles = 2048 blocks
    seg_pred_kernel<<<2048, 256, 0, stream>>>(x, ws, out);
}

// Round 4
// 294.513 us; speedup vs baseline: 1.2346x; 1.2346x over previous
//
#include <hip/hip_runtime.h>

// x        [64, 524288] f32 | idx_feat [4096,256] f32 | weight [64,256] f32
// bias     [64] f32         | pred_cate [4096] i32    | pred_score [4096] f32
// out (f32 concat): seg_pred [53*524288], unique_cate [53], fused_score [53]

#define KK   4096
#define CIN  256
#define CC   64
#define HW   524288   // 512*1024
#define HW2  (HW / 2) // float2 columns
#define UU   53
#define FWS  56       // fwt row stride (53 padded -> 224 B, 16 B aligned rows)

#define CHUNKS 32
#define KPC    (KK / CHUNKS)   // 128 rows per chunk

// ws layout (floats)
#define WS_GSUM 0                    // [53][256] class feature sums
#define WS_GSC  (UU * CIN)           // 13568: [53] score sums (padded to 64)
#define WS_GCNT (WS_GSC + 64)        // [53] counts
#define WS_FWT  (WS_GCNT + 64)       // 13696: fw TRANSPOSED [64][FWS]

// ---------------------------------------------------------------------------
// Stage 1: segment feature sums. Grid (53 classes x 32 k-chunks); each block
// scans 128 pred_cate entries (wave-uniform branch), register-accumulates the
// matching rows (thread tid owns cin=tid), then ONE atomicAdd per thread
// (32 adds per address total -- negligible contention, ~1e-7 reorder noise).
// ---------------------------------------------------------------------------
__global__ __launch_bounds__(256)
void accum_kernel(const float* __restrict__ idx_feat,
                  const int*   __restrict__ pred_cate,
                  float* __restrict__ ws)
{
    const int u   = blockIdx.x;
    const int ch  = blockIdx.y;
    const int tid = threadIdx.x;

    float acc = 0.0f;
    const int k0 = ch * KPC;
    for (int k = k0; k < k0 + KPC; ++k) {
        if (pred_cate[k] == u)                       // uniform branch
            acc += idx_feat[(size_t)k * CIN + tid];  // coalesced row load
    }
    atomicAdd(&ws[WS_GSUM + u * CIN + tid], acc);
}

// ---------------------------------------------------------------------------
// Stage 2: per-class score sum + count. 53 blocks x 64 threads, strided scan
// + wave shuffle reduce (wave=64). Direct writes -> no zeroing needed.
// ---------------------------------------------------------------------------
__global__ __launch_bounds__(64)
void scores_kernel(const int*   __restrict__ pred_cate,
                   const float* __restrict__ pred_score,
                   float* __restrict__ ws)
{
    const int u = blockIdx.x;
    const int t = threadIdx.x;
    float sc = 0.0f, cnt = 0.0f;
    for (int k = t; k < KK; k += 64)
        if (pred_cate[k] == u) { sc += pred_score[k]; cnt += 1.0f; }
    for (int off = 32; off > 0; off >>= 1) {
        sc  += __shfl_down(sc,  off);
        cnt += __shfl_down(cnt, off);
    }
    if (t == 0) { ws[WS_GSC + u] = sc; ws[WS_GCNT + u] = cnt; }
}

// ---------------------------------------------------------------------------
// Stage 3: project class means through weight/bias; write fw TRANSPOSED
// ([c][u], row stride FWS) so the seg kernel reads 53 CONSECUTIVE floats per
// channel (batched s_load_dwordx16 instead of 14 scattered s_load_dword --
// round-3's seg was SMEM-latency-bound on exactly that). Also emits
// unique_cate + fused_score.
// ---------------------------------------------------------------------------
__global__ __launch_bounds__(64)
void project_kernel(const float* __restrict__ ws_ro,
                    const float* __restrict__ weight,
                    const float* __restrict__ bias,
                    float* __restrict__ ws,
                    float* __restrict__ out)
{
    const int u = blockIdx.x;
    const int c = threadIdx.x;
    const float inv = 1.0f / ws_ro[WS_GCNT + u];

    float d = 0.0f;
    #pragma unroll 8
    for (int i = 0; i < CIN; ++i)
        d = fmaf(ws_ro[WS_GSUM + u * CIN + i], weight[(size_t)c * CIN + i], d);
    ws[WS_FWT + c * FWS + u] = d * inv + bias[c];

    if (c == 0) {
        out[(size_t)UU * HW + u]      = (float)u;                 // unique_cate
        out[(size_t)UU * HW + UU + u] = ws_ro[WS_GSC + u] * inv;  // fused_score
    }
}

// ---------------------------------------------------------------------------
// Stage 4: seg_pred = fw [53,64] @ x [64, HW].
// Single pass: thread owns one float2 column, x read EXACTLY once from HBM
// (FETCH ~134 MB), all 53 accumulators in registers (106 VGPR). Per c-iter:
// 1 coalesced dwordx2 load + 53 consecutive wave-uniform fwt floats
// (s_load_dwordx16 batches, prefetched across unroll-2) + 106 FMA.
// Memory floor 242 MB @ 6.3 TB/s = 38.5 us; VALU floor 22.6 us.
// ---------------------------------------------------------------------------
__global__ __launch_bounds__(256)
void seg_pred_kernel(const float* __restrict__ x,
                     const float* __restrict__ ws,
                     float* __restrict__ out)
{
    const int j = blockIdx.x * 256 + threadIdx.x;   // float2 column index
    const float2* x2   = (const float2*)x;
    float2*       out2 = (float2*)out;
    const float*  fwt  = ws + WS_FWT;

    float2 acc[UU];
    #pragma unroll
    for (int u = 0; u < UU; ++u) acc[u] = make_float2(0.0f, 0.0f);

    #pragma unroll 2
    for (int c = 0; c < CC; ++c) {
        const float2 xv = x2[(size_t)c * HW2 + j];
        #pragma unroll
        for (int u = 0; u < UU; ++u) {
            const float w = fwt[c * FWS + u];        // wave-uniform, consecutive
            acc[u].x = fmaf(w, xv.x, acc[u].x);
            acc[u].y = fmaf(w, xv.y, acc[u].y);
        }
    }

    #pragma unroll
    for (int u = 0; u < UU; ++u)
        out2[(size_t)u * HW2 + j] = acc[u];
}

extern "C" void kernel_launch(void* const* d_in, const int* in_sizes, int n_in,
                              void* d_out, int out_size, void* d_ws, size_t ws_size,
                              hipStream_t stream)
{
    const float* x          = (const float*)d_in[0];
    const float* idx_feat   = (const float*)d_in[1];
    const float* weight     = (const float*)d_in[2];
    const float* bias       = (const float*)d_in[3];
    const int*   pred_cate  = (const int*)d_in[4];
    const float* pred_score = (const float*)d_in[5];

    float* out = (float*)d_out;
    float* ws  = (float*)d_ws;

    // zero only the atomic accumulator region (ws re-poisoned 0xAA each call)
    hipMemsetAsync(ws, 0, (size_t)(UU * CIN) * sizeof(float), stream);

    accum_kernel<<<dim3(UU, CHUNKS), 256, 0, stream>>>(idx_feat, pred_cate, ws);
    scores_kernel<<<UU, 64, 0, stream>>>(pred_cate, pred_score, ws);
    project_kernel<<<UU, 64, 0, stream>>>(ws, weight, bias, ws, out);
    seg_pred_kernel<<<HW2 / 256, 256, 0, stream>>>(x, ws, out);
}

// Round 5
// 280.887 us; speedup vs baseline: 1.2945x; 1.0485x over previous
//
#include <hip/hip_runtime.h>

// x        [64, 524288] f32 | idx_feat [4096,256] f32 | weight [64,256] f32
// bias     [64] f32         | pred_cate [4096] i32    | pred_score [4096] f32
// out (f32 concat): seg_pred [53*524288], unique_cate [53], fused_score [53]

#define KK   4096
#define CIN  256
#define CC   64
#define HW   524288   // 512*1024
#define HW4  (HW / 4) // float4 columns
#define UU   53
#define FWS  56       // fwt row stride (53 padded)

#define CHUNKS 32
#define KPC    (KK / CHUNKS)   // 128 rows per chunk

// ws layout (floats)
#define WS_GSUM 0                    // [53][256] class feature sums (atomic)
#define WS_GSC  (UU * CIN)           // 13568: [53] score sums (atomic)
#define WS_GCNT (WS_GSC + 64)        // 13632: [53] counts (atomic)
#define WS_FWT  (WS_GCNT + 64)       // 13696: fw TRANSPOSED [64][FWS]
#define WS_ZERO WS_FWT               // floats to zero

typedef float f4 __attribute__((ext_vector_type(4)));

// ---------------------------------------------------------------------------
// Stage 1: segment feature sums + score/count, fused. Grid (53 x 32 chunks);
// each block scans 128 pred_cate entries (uniform -> s_load batches),
// register-accumulates matching rows (thread owns cin=tid), then one
// atomicAdd per thread (32 adds/address; reorder noise ~1e-7 rel).
// Score/count accumulated uniformly by all threads; lanes 0/1 commit.
// ---------------------------------------------------------------------------
__global__ __launch_bounds__(256)
void accum_kernel(const float* __restrict__ idx_feat,
                  const int*   __restrict__ pred_cate,
                  const float* __restrict__ pred_score,
                  float* __restrict__ ws)
{
    const int u   = blockIdx.x;
    const int ch  = blockIdx.y;
    const int tid = threadIdx.x;

    float acc = 0.0f, sc = 0.0f, cnt = 0.0f;
    const int k0 = ch * KPC;
    #pragma unroll 8
    for (int k = k0; k < k0 + KPC; ++k) {
        if (pred_cate[k] == u) {                      // uniform branch
            acc += idx_feat[(size_t)k * CIN + tid];   // coalesced row load
            sc  += pred_score[k];
            cnt += 1.0f;
        }
    }
    atomicAdd(&ws[WS_GSUM + u * CIN + tid], acc);
    if (tid == 0) atomicAdd(&ws[WS_GSC  + u], sc);
    if (tid == 1) atomicAdd(&ws[WS_GCNT + u], cnt);
}

// ---------------------------------------------------------------------------
// Stage 2: project class means through weight/bias; write fw TRANSPOSED
// ([c][u], stride FWS) so seg reads 53 CONSECUTIVE floats per channel
// (batched s_load_dwordx8/16). Emits unique_cate + fused_score.
// ---------------------------------------------------------------------------
__global__ __launch_bounds__(64)
void project_kernel(const float* __restrict__ ws_ro,
                    const float* __restrict__ weight,
                    const float* __restrict__ bias,
                    float* __restrict__ ws,
                    float* __restrict__ out)
{
    const int u = blockIdx.x;
    const int c = threadIdx.x;
    const float inv = 1.0f / ws_ro[WS_GCNT + u];

    float d = 0.0f;
    #pragma unroll 8
    for (int i = 0; i < CIN; ++i)
        d = fmaf(ws_ro[WS_GSUM + u * CIN + i], weight[(size_t)c * CIN + i], d);
    ws[WS_FWT + c * FWS + u] = d * inv + bias[c];

    if (c == 0) {
        out[(size_t)UU * HW + u]      = (float)u;                 // unique_cate
        out[(size_t)UU * HW + UU + u] = ws_ro[WS_GSC + u] * inv;  // fused_score
    }
}

// ---------------------------------------------------------------------------
// Stage 3: seg_pred = fw [53,64] @ x [64, HW].
// Thread owns one float4 column; x read EXACTLY once (FETCH ~134 MB); all 53
// float4 accumulators in registers (212 VGPR, launch_bounds(256,2) -> 2
// waves/SIMD). x/out are pure streams -> non-temporal to bypass L2.
// Per c-iter: 1 nt dwordx4 load + 53 consecutive uniform fwt floats (sK$)
// + 212 FMA. Floors: mem 245 MB @6.3 TB/s = 39 us; VALU 22.6 us.
// ---------------------------------------------------------------------------
__global__ __launch_bounds__(256, 2)
void seg_pred_kernel(const float* __restrict__ x,
                     const float* __restrict__ ws,
                     float* __restrict__ out)
{
    const int j = blockIdx.x * 256 + threadIdx.x;   // float4 column index
    const f4* x4   = (const f4*)x;
    f4*       out4 = (f4*)out;
    const float* fwt = ws + WS_FWT;

    f4 acc[UU];
    #pragma unroll
    for (int u = 0; u < UU; ++u) acc[u] = (f4)0.0f;

    #pragma unroll 2
    for (int c = 0; c < CC; ++c) {
        const f4 xv = __builtin_nontemporal_load(&x4[(size_t)c * HW4 + j]);
        #pragma unroll
        for (int u = 0; u < UU; ++u) {
            const float w = fwt[c * FWS + u];        // uniform, consecutive
            acc[u].x = fmaf(w, xv.x, acc[u].x);
            acc[u].y = fmaf(w, xv.y, acc[u].y);
            acc[u].z = fmaf(w, xv.z, acc[u].z);
            acc[u].w = fmaf(w, xv.w, acc[u].w);
        }
    }

    #pragma unroll
    for (int u = 0; u < UU; ++u)
        __builtin_nontemporal_store(acc[u], &out4[(size_t)u * HW4 + j]);
}

extern "C" void kernel_launch(void* const* d_in, const int* in_sizes, int n_in,
                              void* d_out, int out_size, void* d_ws, size_t ws_size,
                              hipStream_t stream)
{
    const float* x          = (const float*)d_in[0];
    const float* idx_feat   = (const float*)d_in[1];
    const float* weight     = (const float*)d_in[2];
    const float* bias       = (const float*)d_in[3];
    const int*   pred_cate  = (const int*)d_in[4];
    const float* pred_score = (const float*)d_in[5];

    float* out = (float*)d_out;
    float* ws  = (float*)d_ws;

    // zero the atomic accumulator region (ws re-poisoned 0xAA each call)
    hipMemsetAsync(ws, 0, (size_t)WS_ZERO * sizeof(float), stream);

    accum_kernel<<<dim3(UU, CHUNKS), 256, 0, stream>>>(idx_feat, pred_cate,
                                                       pred_score, ws);
    project_kernel<<<UU, 64, 0, stream>>>(ws, weight, bias, ws, out);
    seg_pred_kernel<<<HW4 / 256, 256, 0, stream>>>(x, ws, out);  // 512 blocks
}